// Round 2
// 1509.092 us; speedup vs baseline: 1.1588x; 1.1588x over previous
//
#include <hip/hip_runtime.h>

// Problem constants
#define BD (1024LL * 1024LL)   // B*D elements per node-plane

using bf16x8 = __attribute__((ext_vector_type(8))) __bf16;
using f32x4  = __attribute__((ext_vector_type(4))) float;

__device__ __forceinline__ unsigned short f2bf(float f) {
  unsigned int u = __float_as_uint(f);
  u += 0x7fffu + ((u >> 16) & 1u);   // RNE
  return (unsigned short)(u >> 16);
}
__device__ __forceinline__ float bf2f(unsigned short h) {
  return __uint_as_float((unsigned int)h << 16);
}

// async global->LDS, 16B per lane; lptr must be wave-uniform, lanes land at +lane*16
__device__ __forceinline__ void gl_lds16(const unsigned short* g, unsigned short* l) {
  __builtin_amdgcn_global_load_lds(
      (const __attribute__((address_space(1))) void*)g,
      (__attribute__((address_space(3))) void*)l, 16, 0, 0);
}

// ---------------------------------------------------------------------------
// fp32 -> bf16 bulk convert (weights), n4 = element_count/4
__global__ __launch_bounds__(256) void cvt_kernel(const float* __restrict__ src,
                                                  unsigned short* __restrict__ dst,
                                                  long long n4) {
  long long i = (long long)blockIdx.x * 256 + threadIdx.x;
  if (i >= n4) return;
  float4 v = *(const float4*)(src + i * 4);
  unsigned int lo = (unsigned int)f2bf(v.x) | ((unsigned int)f2bf(v.y) << 16);
  unsigned int hi = (unsigned int)f2bf(v.z) | ((unsigned int)f2bf(v.w) << 16);
  *(uint2*)(dst + i * 4) = make_uint2(lo, hi);
}

// ---------------------------------------------------------------------------
// Transposing cvt: dst[n][j][k] (bf16) = src[n][k][j] (fp32), 1024x1024 per node
__global__ __launch_bounds__(256) void tcvt_kernel(const float* __restrict__ src,
                                                   unsigned short* __restrict__ dst) {
  __shared__ float tile[32][33];
  const int n = blockIdx.z;
  const int bk = blockIdx.y * 32;   // source-row block
  const int bj = blockIdx.x * 32;   // source-col block
  const int tx = threadIdx.x & 31;
  const int ty = threadIdx.x >> 5;  // 0..7
#pragma unroll
  for (int r = 0; r < 4; ++r)
    tile[ty + r * 8][tx] = src[(long long)n * BD + (long long)(bk + ty + r * 8) * 1024 + bj + tx];
  __syncthreads();
#pragma unroll
  for (int r = 0; r < 4; ++r)
    dst[(long long)n * BD + (long long)(bj + ty + r * 8) * 1024 + bk + tx] =
        f2bf(tile[tx][ty + r * 8]);
}

// ---------------------------------------------------------------------------
// Combined attention bias: cb[n][i] = o_b[n][i] + sum_k o_w[n][i][k] * v_b[n][k]
__global__ __launch_bounds__(256) void cb_kernel(const float* __restrict__ o_w,
                                                 const float* __restrict__ v_b,
                                                 const float* __restrict__ o_b,
                                                 float* __restrict__ cb) {
  const int n = blockIdx.y;
  const int i = blockIdx.x * 4 + (threadIdx.x >> 6);
  const int lane = threadIdx.x & 63;
  const float* row = o_w + (long long)n * BD + (long long)i * 1024;
  const float* vb = v_b + n * 1024;
  float s = 0.f;
#pragma unroll
  for (int t = 0; t < 16; ++t) s += row[lane + t * 64] * vb[lane + t * 64];
  for (int off = 32; off > 0; off >>= 1) s += __shfl_down(s, off);
  if (lane == 0) cb[n * 1024 + i] = o_b[n * 1024 + i] + s;
}

// ---------------------------------------------------------------------------
// Init: S = 0 except node 4 = seed; mem = 0.  Covers 13*BD floats as float4.
__global__ __launch_bounds__(256) void init_kernel(const float* __restrict__ seed,
                                                   float* __restrict__ S,
                                                   float* __restrict__ mem) {
  long long i = (long long)blockIdx.x * 256 + threadIdx.x;  // float4 index
  const long long S4 = 9 * BD / 4;
  if (i < S4) {
    float4 v = make_float4(0.f, 0.f, 0.f, 0.f);
    const long long lo4 = 4 * BD / 4, hi4 = 5 * BD / 4;
    if (i >= lo4 && i < hi4) v = *(const float4*)(seed + (i - lo4) * 4);
    *(float4*)(S + i * 4) = v;
  } else {
    long long j = i - S4;
    *(float4*)(mem + j * 4) = make_float4(0.f, 0.f, 0.f, 0.f);
  }
}

// ---------------------------------------------------------------------------
// LayerNorm over D=1024, one (node,row) per 256-thread block.
// ADJ=true: input = neighbor-sum of S (3x3 grid), also writes integ (fp32).
template <bool ADJ>
__global__ __launch_bounds__(256) void ln_kernel(const float* __restrict__ in,
                                                 const float* __restrict__ gam,
                                                 const float* __restrict__ bet,
                                                 float* __restrict__ integ,
                                                 unsigned short* __restrict__ out) {
  const int row = blockIdx.x;
  const int node = blockIdx.y;
  const int tid = threadIdx.x;
  const long long rowoff = (long long)row * 1024 + tid * 4;
  const long long base = (long long)node * BD + rowoff;
  float4 v;
  if (ADJ) {
    v = make_float4(0.f, 0.f, 0.f, 0.f);
    const int r = node / 3, c = node % 3;
    if (r > 0) { float4 t = *(const float4*)(in + (node - 3) * BD + rowoff); v.x += t.x; v.y += t.y; v.z += t.z; v.w += t.w; }
    if (r < 2) { float4 t = *(const float4*)(in + (node + 3) * BD + rowoff); v.x += t.x; v.y += t.y; v.z += t.z; v.w += t.w; }
    if (c > 0) { float4 t = *(const float4*)(in + (node - 1) * BD + rowoff); v.x += t.x; v.y += t.y; v.z += t.z; v.w += t.w; }
    if (c < 2) { float4 t = *(const float4*)(in + (node + 1) * BD + rowoff); v.x += t.x; v.y += t.y; v.z += t.z; v.w += t.w; }
    *(float4*)(integ + base) = v;
  } else {
    v = *(const float4*)(in + base);
  }
  float s = v.x + v.y + v.z + v.w;
  float q = v.x * v.x + v.y * v.y + v.z * v.z + v.w * v.w;
  for (int off = 32; off > 0; off >>= 1) {
    s += __shfl_down(s, off);
    q += __shfl_down(q, off);
  }
  __shared__ float red[8];
  if ((tid & 63) == 0) { red[tid >> 6] = s; red[4 + (tid >> 6)] = q; }
  __syncthreads();
  s = red[0] + red[1] + red[2] + red[3];
  q = red[4] + red[5] + red[6] + red[7];
  const float mean = s * (1.0f / 1024.0f);
  const float var = q * (1.0f / 1024.0f) - mean * mean;
  const float inv = rsqrtf(var + 1e-5f);
  const float4 g = *(const float4*)(gam + node * 1024 + tid * 4);
  const float4 b = *(const float4*)(bet + node * 1024 + tid * 4);
  const float o0 = (v.x - mean) * inv * g.x + b.x;
  const float o1 = (v.y - mean) * inv * g.y + b.y;
  const float o2 = (v.z - mean) * inv * g.z + b.z;
  const float o3 = (v.w - mean) * inv * g.w + b.w;
  unsigned int lo = (unsigned int)f2bf(o0) | ((unsigned int)f2bf(o1) << 16);
  unsigned int hi = (unsigned int)f2bf(o2) | ((unsigned int)f2bf(o3) << 16);
  *(uint2*)(out + base) = make_uint2(lo, hi);
}

// ---------------------------------------------------------------------------
// Batched bf16 MFMA GEMM, 128x128 tile (kept for attention + wc precompute).
// MODE 1: out fp32 = add + acc + bias; memory-node EMA   (attention, SK=1)
// MODE 4: out bf16 = acc  (no bias)
template <int MODE>
__global__ __launch_bounds__(256, 3) void gemm_kernel(
    const unsigned short* __restrict__ X, long long sX,
    const unsigned short* __restrict__ W, long long sW,
    const float* __restrict__ bias, int sBias,
    const float* __restrict__ add, long long sAdd,
    float* __restrict__ memio,
    void* __restrict__ outp, long long sOut,
    int N, int K, int SK) {
  __shared__ unsigned short Als[128 * 32];
  __shared__ unsigned short Bls[128 * 32];
  const int z = blockIdx.z;
  const int node = z / SK;
  const int kz = z - node * SK;
  const int Kper = K / SK;
  const int kbeg = kz * Kper;
  const long long bm = (long long)blockIdx.y * 128;
  const long long bn = (long long)blockIdx.x * 128;
  const unsigned short* Xz = X + (long long)node * sX;
  const unsigned short* Wz = W + (long long)node * sW;
  const int tid = threadIdx.x;
  const int lane = tid & 63;
  const int wid = tid >> 6;
  const int wm = (wid >> 1) * 64;
  const int wn = (wid & 1) * 64;
  const int lm = lane & 15;
  const int quad = lane >> 4;

  f32x4 acc[4][4] = {};

  const int lrow = lane >> 2;
  const int gch = ((lane & 3) ^ ((lane >> 3) & 3)) * 8;  // swizzled global k-offset
  const int fch = (quad ^ ((lm >> 1) & 3)) * 8;          // fragment-read chunk

  for (int k0 = kbeg; k0 < kbeg + Kper; k0 += 32) {
    __syncthreads();
#pragma unroll
    for (int t = 0; t < 2; ++t) {
      const int idx = wid * 2 + t;
      const long long row = idx * 16 + lrow;
      gl_lds16(Xz + (bm + row) * K + k0 + gch, &Als[idx * 512]);
      gl_lds16(Wz + (bn + row) * K + k0 + gch, &Bls[idx * 512]);
    }
    __syncthreads();
    bf16x8 af[4], bfv[4];
#pragma unroll
    for (int i = 0; i < 4; ++i)
      af[i] = *(const bf16x8*)&Als[(wm + i * 16 + lm) * 32 + fch];
#pragma unroll
    for (int j = 0; j < 4; ++j)
      bfv[j] = *(const bf16x8*)&Bls[(wn + j * 16 + lm) * 32 + fch];
#pragma unroll
    for (int i = 0; i < 4; ++i)
#pragma unroll
      for (int j = 0; j < 4; ++j)
        acc[i][j] = __builtin_amdgcn_mfma_f32_16x16x32_bf16(af[i], bfv[j], acc[i][j], 0, 0, 0);
  }

  // Epilogue.  C/D layout: col = lane&15, row = quad*4 + reg  (HW-verified)
  if (MODE == 4) {
    unsigned short* out = (unsigned short*)outp + (long long)z * sOut;
#pragma unroll
    for (int i = 0; i < 4; ++i) {
      const long long rb = bm + wm + i * 16 + quad * 4;
#pragma unroll
      for (int j = 0; j < 4; ++j) {
        const int col = (int)bn + wn + j * 16 + lm;
#pragma unroll
        for (int r = 0; r < 4; ++r)
          out[(rb + r) * (long long)N + col] = f2bf(acc[i][j][r]);
      }
    }
  } else {  // MODE 1
    const float* bz = bias + (long long)node * sBias;
    float* out = (float*)outp + (long long)node * sOut;
    const float* az = add + (long long)node * sAdd;
    const bool is_mem = (node != 4) && ((node & 1) == 0);
    float* mz = nullptr;
    if (is_mem) {
      const int mi = (node == 0) ? 0 : (node == 2) ? 1 : (node == 6) ? 2 : 3;
      mz = memio + (long long)mi * BD;
    }
#pragma unroll
    for (int i = 0; i < 4; ++i) {
      const long long rb = bm + wm + i * 16 + quad * 4;
#pragma unroll
      for (int j = 0; j < 4; ++j) {
        const int col = (int)bn + wn + j * 16 + lm;
        const float bv = bz[col];
#pragma unroll
        for (int r = 0; r < 4; ++r) {
          const long long idx = (rb + r) * (long long)N + col;
          float v = acc[i][j][r] + bv + az[idx];
          if (is_mem) {
            v = 0.7f * mz[idx] + 0.3f * v;
            mz[idx] = v;
          }
          out[idx] = v;
        }
      }
    }
  }
}

// ---------------------------------------------------------------------------
// 256x256 / BK=64 8-phase pipelined GEMM (HK-style schedule, plain HIP).
// 512 threads = 8 waves (2M x 4N), per-wave output 128x64 (acc[8][4]).
// LDS 128 KiB: [buf][A/B][khalf][256 rows x 32 bf16], chunk-XOR swizzled
// (same proven conflict-free scheme as the 128^2 kernel). Staging via
// global_load_lds 16B, 1 half-tile (2 loads) per phase; counted vmcnt(6)
// at phases 4/8 only (never 0 in steady state); setprio around MFMA.
// MODE 2: out bf16 = relu(acc + bias)     (FFN layer 1)
// MODE 4: out bf16 = acc (no bias)        (split-K partials)
template <int MODE>
__global__ __launch_bounds__(512, 2) void gemm256_kernel(
    const unsigned short* __restrict__ X, long long sX,
    const unsigned short* __restrict__ W, long long sW,
    const float* __restrict__ bias, int sBias,
    void* __restrict__ outp, long long sOut,
    int N, int K, int SK) {
  __shared__ __attribute__((aligned(16))) unsigned short lds[2][2][2][8192];
  const int z = blockIdx.z;
  const int node = z / SK;
  const int kz = z - node * SK;
  const int Kper = K / SK;
  const int kbeg = kz * Kper;
  const long long bm = (long long)blockIdx.y * 256;
  const long long bn = (long long)blockIdx.x * 256;
  const unsigned short* Xz = X + (long long)node * sX;
  const unsigned short* Wz = W + (long long)node * sW;
  const int tid = threadIdx.x;
  const int lane = tid & 63;
  const int wid = tid >> 6;
  const int wrow = (wid >> 2) * 128;   // wave M base within tile
  const int wcol = (wid & 3) * 64;     // wave N base within tile
  const int lm = lane & 15;
  const int quad = lane >> 4;
  const int lrow = lane >> 2;
  const int gch = ((lane & 3) ^ ((lane >> 3) & 3)) * 8;  // swizzled global k-chunk
  const int fch = (quad ^ ((lm >> 1) & 3)) * 8;          // fragment-read chunk

  f32x4 acc[8][4] = {};
  bf16x8 af[4][2], bfv[4][2];

  // per-wave 16-row staging groups
  const int GA = (wid & 3) + ((wid >> 2) << 3);       // A0: {0-3,8-11}; A1 = +4
  const int GB = ((wid >> 1) << 2) + (wid & 1);       // B0: {0,1,4,5,...}; B1 = +2
  const unsigned short* pA[2] = {
      Xz + (bm + (long long)GA * 16 + lrow) * K + gch,
      Xz + (bm + (long long)(GA + 4) * 16 + lrow) * K + gch };
  const unsigned short* pB[2] = {
      Wz + (bn + (long long)GB * 16 + lrow) * K + gch,
      Wz + (bn + (long long)(GB + 2) * 16 + lrow) * K + gch };
  const int dA[2] = { GA * 512, (GA + 4) * 512 };
  const int dB[2] = { GB * 512, (GB + 2) * 512 };

  // one half-tile = 128 rows x 64 cols = 2 x global_load_lds (kh0, kh1)
  auto stageA = [&](int buf, int t, int hi) {
    const unsigned short* g = pA[hi] + kbeg + (long long)t * 64;
    gl_lds16(g,      &lds[buf][0][0][dA[hi]]);
    gl_lds16(g + 32, &lds[buf][0][1][dA[hi]]);
  };
  auto stageB = [&](int buf, int t, int hi) {
    const unsigned short* g = pB[hi] + kbeg + (long long)t * 64;
    gl_lds16(g,      &lds[buf][1][0][dB[hi]]);
    gl_lds16(g + 32, &lds[buf][1][1][dB[hi]]);
  };

#define LDA_HALF(BUF, IH)                                                      \
  _Pragma("unroll") for (int i_ = 0; i_ < 4; ++i_)                             \
      _Pragma("unroll") for (int k_ = 0; k_ < 2; ++k_)                         \
          af[i_][k_] = *(const bf16x8*)&lds[BUF][0][k_]                        \
              [(wrow + (IH) * 64 + i_ * 16 + lm) * 32 + fch];

#define LDB_HALF(BUF, JH)                                                      \
  _Pragma("unroll") for (int j_ = 0; j_ < 2; ++j_)                             \
      _Pragma("unroll") for (int k_ = 0; k_ < 2; ++k_)                         \
          bfv[(JH) * 2 + j_][k_] = *(const bf16x8*)&lds[BUF][1][k_]            \
              [(wcol + (JH) * 32 + j_ * 16 + lm) * 32 + fch];

#define MFMA_Q(IH, JH)                                                         \
  _Pragma("unroll") for (int i_ = 0; i_ < 4; ++i_)                             \
      _Pragma("unroll") for (int j_ = 0; j_ < 2; ++j_)                         \
          _Pragma("unroll") for (int k_ = 0; k_ < 2; ++k_)                     \
              acc[(IH) * 4 + i_][(JH) * 2 + j_] =                              \
                  __builtin_amdgcn_mfma_f32_16x16x32_bf16(                     \
                      af[i_][k_], bfv[(JH) * 2 + j_][k_],                      \
                      acc[(IH) * 4 + i_][(JH) * 2 + j_], 0, 0, 0);

#define PH_MID()                                          \
  __builtin_amdgcn_s_barrier();                           \
  asm volatile("s_waitcnt lgkmcnt(0)" ::: "memory");      \
  __builtin_amdgcn_s_setprio(1);

#define PH_END()                                          \
  __builtin_amdgcn_s_setprio(0);                          \
  __builtin_amdgcn_s_barrier();

  const int NIT = Kper >> 7;   // tile-pairs (2 x BK=64 per iteration)

  // Prologue: tile 0 fully (A0,B0,B1,A1) + tile 1 (A0,B0,B1) = 14 loads.
  stageA(0, 0, 0); stageB(0, 0, 0); stageB(0, 0, 1); stageA(0, 0, 1);
  stageA(1, 1, 0); stageB(1, 1, 0); stageB(1, 1, 1);
  asm volatile("s_waitcnt vmcnt(6)" ::: "memory");   // tile 0 landed
  __builtin_amdgcn_s_barrier();

#pragma unroll 1
  for (int I = 0; I < NIT; ++I) {
    const bool notlast = (I + 1 < NIT);
    const int t0 = 2 * I;
    // phase 1: Q(0,0) of tile t0 (buf0); stage A1 of tile t0+1 -> buf1
    LDA_HALF(0, 0) LDB_HALF(0, 0)
    stageA(1, t0 + 1, 1);
    PH_MID() MFMA_Q(0, 0) PH_END()
    // phase 2: Q(0,1); stage A0 of t0+2 -> buf0 (region read in ph1)
    LDB_HALF(0, 1)
    if (notlast) stageA(0, t0 + 2, 0);
    PH_MID() MFMA_Q(0, 1) PH_END()
    // phase 3: Q(1,0); stage B0 of t0+2
    LDA_HALF(0, 1)
    if (notlast) stageB(0, t0 + 2, 0);
    PH_MID() MFMA_Q(1, 0) PH_END()
    // phase 4: Q(1,1); stage B1 of t0+2; counted wait for tile t0+1
    if (notlast) stageB(0, t0 + 2, 1);
    PH_MID() MFMA_Q(1, 1)
    __builtin_amdgcn_s_setprio(0);
    if (notlast) asm volatile("s_waitcnt vmcnt(6)" ::: "memory");
    else         asm volatile("s_waitcnt vmcnt(0)" ::: "memory");
    __builtin_amdgcn_s_barrier();
    // phase 5: Q(0,0) of tile t0+1 (buf1); stage A1 of t0+2
    LDA_HALF(1, 0) LDB_HALF(1, 0)
    if (notlast) stageA(0, t0 + 2, 1);
    PH_MID() MFMA_Q(0, 0) PH_END()
    // phase 6: Q(0,1); stage A0 of t0+3 -> buf1
    LDB_HALF(1, 1)
    if (notlast) stageA(1, t0 + 3, 0);
    PH_MID() MFMA_Q(0, 1) PH_END()
    // phase 7: Q(1,0); stage B0 of t0+3
    LDA_HALF(1, 1)
    if (notlast) stageB(1, t0 + 3, 0);
    PH_MID() MFMA_Q(1, 0) PH_END()
    // phase 8: Q(1,1); stage B1 of t0+3; counted wait for tile t0+2
    if (notlast) stageB(1, t0 + 3, 1);
    PH_MID() MFMA_Q(1, 1)
    __builtin_amdgcn_s_setprio(0);
    if (notlast) asm volatile("s_waitcnt vmcnt(6)" ::: "memory");
    __builtin_amdgcn_s_barrier();
  }

  // Epilogue.  C/D layout: col = lane&15, row = quad*4 + reg
  if (MODE == 2) {
    const float* bz = bias + (long long)node * sBias;
    unsigned short* out = (unsigned short*)outp + (long long)node * sOut;
#pragma unroll
    for (int i = 0; i < 8; ++i) {
      const long long rb = bm + wrow + i * 16 + quad * 4;
#pragma unroll
      for (int j = 0; j < 4; ++j) {
        const int col = (int)bn + wcol + j * 16 + lm;
        const float bv = bz[col];
#pragma unroll
        for (int r = 0; r < 4; ++r)
          out[(rb + r) * (long long)N + col] = f2bf(fmaxf(acc[i][j][r] + bv, 0.0f));
      }
    }
  } else {  // MODE 4
    unsigned short* out = (unsigned short*)outp + (long long)z * sOut;
#pragma unroll
    for (int i = 0; i < 8; ++i) {
      const long long rb = bm + wrow + i * 16 + quad * 4;
#pragma unroll
      for (int j = 0; j < 4; ++j) {
        const int col = (int)bn + wcol + j * 16 + lm;
#pragma unroll
        for (int r = 0; r < 4; ++r)
          out[(rb + r) * (long long)N + col] = f2bf(acc[i][j][r]);
      }
    }
  }
#undef LDA_HALF
#undef LDB_HALF
#undef MFMA_Q
#undef PH_MID
#undef PH_END
}

// ---------------------------------------------------------------------------
// Split-K reduce: S[node] += sum_kz partial[kz] + bias.  bf16 partials.
__global__ __launch_bounds__(256) void reduce_kernel(const unsigned short* __restrict__ part_s,
                                                     const unsigned short* __restrict__ part_e,
                                                     const float* __restrict__ b2s,
                                                     const float* __restrict__ b2e,
                                                     float* __restrict__ S) {
  const int node = blockIdx.y;
  const long long i8 = ((long long)blockIdx.x * 256 + threadIdx.x) * 8;
  const int col = (int)(i8 & 1023);
  const unsigned short* base;
  const float* bias;
  int SKn;
  if (node & 1) {
    const int e = (node - 1) >> 1;
    base = part_e + (long long)(e * 4) * BD + i8;
    bias = b2e + e * 1024;
    SKn = 4;
  } else {
    const int si = node >> 1;
    base = part_s + (long long)(si * 2) * BD + i8;
    bias = b2s + si * 1024;
    SKn = 2;
  }
  float sum[8] = {};
  for (int kz = 0; kz < SKn; ++kz) {
    uint4 p = *(const uint4*)(base + (long long)kz * BD);
    const unsigned short* ph = (const unsigned short*)&p;
#pragma unroll
    for (int j = 0; j < 8; ++j) sum[j] += bf2f(ph[j]);
  }
  float* sp = S + (long long)node * BD + i8;
  float4 s0 = *(float4*)sp;
  float4 s1 = *(float4*)(sp + 4);
  s0.x += sum[0] + bias[col + 0];
  s0.y += sum[1] + bias[col + 1];
  s0.z += sum[2] + bias[col + 2];
  s0.w += sum[3] + bias[col + 3];
  s1.x += sum[4] + bias[col + 4];
  s1.y += sum[5] + bias[col + 5];
  s1.z += sum[6] + bias[col + 6];
  s1.w += sum[7] + bias[col + 7];
  *(float4*)sp = s0;
  *(float4*)(sp + 4) = s1;
}

// ---------------------------------------------------------------------------
extern "C" void kernel_launch(void* const* d_in, const int* in_sizes, int n_in,
                              void* d_out, int out_size, void* d_ws, size_t ws_size,
                              hipStream_t stream) {
  const float* seed  = (const float*)d_in[0];
  const float* ln1_s = (const float*)d_in[1];
  const float* ln1_b = (const float*)d_in[2];
  const float* v_w   = (const float*)d_in[3];
  const float* v_b   = (const float*)d_in[4];
  const float* o_w   = (const float*)d_in[5];
  const float* o_b   = (const float*)d_in[6];
  const float* ln2_s = (const float*)d_in[7];
  const float* ln2_b = (const float*)d_in[8];
  const float* w1_s  = (const float*)d_in[9];
  const float* b1_s  = (const float*)d_in[10];
  const float* w2_s  = (const float*)d_in[11];
  const float* b2_s  = (const float*)d_in[12];
  const float* w1_e  = (const float*)d_in[13];
  const float* b1_e  = (const float*)d_in[14];
  const float* w2_e  = (const float*)d_in[15];
  const float* b2_e  = (const float*)d_in[16];

  char* ws = (char*)d_ws;
  size_t off = 0;
  auto alloc = [&](long long elems, int esize) {
    void* p = ws + off;
    off += (size_t)((elems * esize + 255LL) & ~255LL);
    return p;
  };
  unsigned short* wo    = (unsigned short*)alloc(9 * BD, 2);
  unsigned short* vwT   = (unsigned short*)alloc(9 * BD, 2);
  unsigned short* wc    = (unsigned short*)alloc(9 * BD, 2);
  unsigned short* w1s   = (unsigned short*)alloc(10 * BD, 2);
  unsigned short* w2s   = (unsigned short*)alloc(10 * BD, 2);
  unsigned short* w1e   = (unsigned short*)alloc(32 * BD, 2);
  unsigned short* w2e   = (unsigned short*)alloc(32 * BD, 2);
  float*          membuf= (float*)alloc(4 * BD, 4);
  float*          cb    = (float*)alloc(9 * 1024, 4);
  // union region: {integ fp32 + xn bf16} (54 MB)  <->  {part_s + part_e} (52 MB)
  char* region = (char*)alloc(9 * BD * 4 + 9 * BD * 2, 1);
  float*          integ  = (float*)region;
  unsigned short* xn     = (unsigned short*)(region + 9 * BD * 4);
  unsigned short* part_s = (unsigned short*)region;                 // 10 planes bf16
  unsigned short* part_e = (unsigned short*)(region + 10 * BD * 2); // 16 planes bf16
  unsigned short* hs    = (unsigned short*)alloc(10 * BD, 2);
  unsigned short* he    = (unsigned short*)alloc(32 * BD, 2);

  float* S = (float*)d_out;  // S lives in d_out; also aliases x within a step

  // One-time (per launch): weight conversion, combined attention weight, init
  cvt_kernel<<<(unsigned)(9  * BD / 1024), 256, 0, stream>>>(o_w,  wo,  9  * BD / 4);
  tcvt_kernel<<<dim3(32, 32, 9), 256, 0, stream>>>(v_w, vwT);
  cvt_kernel<<<(unsigned)(10 * BD / 1024), 256, 0, stream>>>(w1_s, w1s, 10 * BD / 4);
  cvt_kernel<<<(unsigned)(10 * BD / 1024), 256, 0, stream>>>(w2_s, w2s, 10 * BD / 4);
  cvt_kernel<<<(unsigned)(32 * BD / 1024), 256, 0, stream>>>(w1_e, w1e, 32 * BD / 4);
  cvt_kernel<<<(unsigned)(32 * BD / 1024), 256, 0, stream>>>(w2_e, w2e, 32 * BD / 4);
  cb_kernel<<<dim3(256, 9), 256, 0, stream>>>(o_w, v_b, o_b, cb);
  // wc[n] = o_w[n] . v_w[n]  (combined attention weight, bf16)
  gemm_kernel<4><<<dim3(8, 8, 9), 256, 0, stream>>>(
      wo, BD, vwT, BD, nullptr, 0, nullptr, 0, nullptr, (void*)wc, BD, 1024, 1024, 1);
  init_kernel<<<(unsigned)(13 * BD / 1024), 256, 0, stream>>>(seed, S, membuf);

  for (int step = 0; step < 3; ++step) {
    // integ = A@S ; xn = LN1(integ)
    ln_kernel<true><<<dim3(1024, 9), 256, 0, stream>>>(S, ln1_s, ln1_b, integ, xn);
    // x = integ + xn @ wc^T + cb ; memory-node EMA mix; writes S(=x) and mem
    gemm_kernel<1><<<dim3(8, 8, 9), 256, 0, stream>>>(
        xn, BD, wc, BD, cb, 1024, integ, BD, membuf, (void*)S, BD, 1024, 1024, 1);
    // xn2 = LN2(x)
    ln_kernel<false><<<dim3(1024, 9), 256, 0, stream>>>(S, ln2_s, ln2_b, nullptr, xn);
    // hs = relu(xn2[sids] @ w1_s^T + b1_s)   nodes {0,2,4,6,8}
    gemm256_kernel<2><<<dim3(8, 4, 5), 512, 0, stream>>>(
        xn, 2 * BD, w1s, 2 * BD, b1_s, 2048, (void*)hs, 2 * BD, 2048, 1024, 1);
    // he = relu(xn2[eids] @ w1_e^T + b1_e)   nodes {1,3,5,7}
    gemm256_kernel<2><<<dim3(32, 4, 4), 512, 0, stream>>>(
        xn + BD, 2 * BD, w1e, 8 * BD, b1_e, 8192, (void*)he, 8 * BD, 8192, 1024, 1);
    // split-K partials: part_s[si*2+kz] = (hs @ w2_s^T)  (160 blocks)
    gemm256_kernel<4><<<dim3(4, 4, 10), 512, 0, stream>>>(
        hs, 2 * BD, w2s, 2 * BD, nullptr, 0, (void*)part_s, BD, 1024, 2048, 2);
    // split-K partials: part_e[e*4+kz] = (he @ w2_e^T)   (256 blocks)
    gemm256_kernel<4><<<dim3(4, 4, 16), 512, 0, stream>>>(
        he, 8 * BD, w2e, 8 * BD, nullptr, 0, (void*)part_e, BD, 1024, 8192, 4);
    // S += sum(partials) + b2
    reduce_kernel<<<dim3(512, 9), 256, 0, stream>>>(part_s, part_e, b2_s, b2_e, S);
  }
}

// Round 6
// 1396.035 us; speedup vs baseline: 1.2527x; 1.0810x over previous
//
#include <hip/hip_runtime.h>

// Problem constants
#define BD (1024LL * 1024LL)   // B*D elements per node-plane

using bf16x8 = __attribute__((ext_vector_type(8))) __bf16;
using f32x4  = __attribute__((ext_vector_type(4))) float;

__device__ __forceinline__ unsigned short f2bf(float f) {
  unsigned int u = __float_as_uint(f);
  u += 0x7fffu + ((u >> 16) & 1u);   // RNE
  return (unsigned short)(u >> 16);
}
__device__ __forceinline__ float bf2f(unsigned short h) {
  return __uint_as_float((unsigned int)h << 16);
}

// async global->LDS, 16B per lane; lptr must be wave-uniform, lanes land at +lane*16
__device__ __forceinline__ void gl_lds16(const unsigned short* g, unsigned short* l) {
  __builtin_amdgcn_global_load_lds(
      (const __attribute__((address_space(1))) void*)g,
      (__attribute__((address_space(3))) void*)l, 16, 0, 0);
}

// ---------------------------------------------------------------------------
// fp32 -> bf16 bulk convert (weights), n4 = element_count/4
__global__ __launch_bounds__(256) void cvt_kernel(const float* __restrict__ src,
                                                  unsigned short* __restrict__ dst,
                                                  long long n4) {
  long long i = (long long)blockIdx.x * 256 + threadIdx.x;
  if (i >= n4) return;
  float4 v = *(const float4*)(src + i * 4);
  unsigned int lo = (unsigned int)f2bf(v.x) | ((unsigned int)f2bf(v.y) << 16);
  unsigned int hi = (unsigned int)f2bf(v.z) | ((unsigned int)f2bf(v.w) << 16);
  *(uint2*)(dst + i * 4) = make_uint2(lo, hi);
}

// ---------------------------------------------------------------------------
// Transposing cvt: dst[n][j][k] (bf16) = src[n][k][j] (fp32), 1024x1024 per node
__global__ __launch_bounds__(256) void tcvt_kernel(const float* __restrict__ src,
                                                   unsigned short* __restrict__ dst) {
  __shared__ float tile[32][33];
  const int n = blockIdx.z;
  const int bk = blockIdx.y * 32;   // source-row block
  const int bj = blockIdx.x * 32;   // source-col block
  const int tx = threadIdx.x & 31;
  const int ty = threadIdx.x >> 5;  // 0..7
#pragma unroll
  for (int r = 0; r < 4; ++r)
    tile[ty + r * 8][tx] = src[(long long)n * BD + (long long)(bk + ty + r * 8) * 1024 + bj + tx];
  __syncthreads();
#pragma unroll
  for (int r = 0; r < 4; ++r)
    dst[(long long)n * BD + (long long)(bj + ty + r * 8) * 1024 + bk + tx] =
        f2bf(tile[tx][ty + r * 8]);
}

// ---------------------------------------------------------------------------
// Combined attention bias: cb[n][i] = o_b[n][i] + sum_k o_w[n][i][k] * v_b[n][k]
__global__ __launch_bounds__(256) void cb_kernel(const float* __restrict__ o_w,
                                                 const float* __restrict__ v_b,
                                                 const float* __restrict__ o_b,
                                                 float* __restrict__ cb) {
  const int n = blockIdx.y;
  const int i = blockIdx.x * 4 + (threadIdx.x >> 6);
  const int lane = threadIdx.x & 63;
  const float* row = o_w + (long long)n * BD + (long long)i * 1024;
  const float* vb = v_b + n * 1024;
  float s = 0.f;
#pragma unroll
  for (int t = 0; t < 16; ++t) s += row[lane + t * 64] * vb[lane + t * 64];
  for (int off = 32; off > 0; off >>= 1) s += __shfl_down(s, off);
  if (lane == 0) cb[n * 1024 + i] = o_b[n * 1024 + i] + s;
}

// ---------------------------------------------------------------------------
// Init: S = 0 except node 4 = seed; mem = 0.  Covers 13*BD floats as float4.
__global__ __launch_bounds__(256) void init_kernel(const float* __restrict__ seed,
                                                   float* __restrict__ S,
                                                   float* __restrict__ mem) {
  long long i = (long long)blockIdx.x * 256 + threadIdx.x;  // float4 index
  const long long S4 = 9 * BD / 4;
  if (i < S4) {
    float4 v = make_float4(0.f, 0.f, 0.f, 0.f);
    const long long lo4 = 4 * BD / 4, hi4 = 5 * BD / 4;
    if (i >= lo4 && i < hi4) v = *(const float4*)(seed + (i - lo4) * 4);
    *(float4*)(S + i * 4) = v;
  } else {
    long long j = i - S4;
    *(float4*)(mem + j * 4) = make_float4(0.f, 0.f, 0.f, 0.f);
  }
}

// ---------------------------------------------------------------------------
// LayerNorm over D=1024, one (node,row) per 256-thread block.
// ADJ=true: input = neighbor-sum of S (3x3 grid), also writes integ (fp32).
template <bool ADJ>
__global__ __launch_bounds__(256) void ln_kernel(const float* __restrict__ in,
                                                 const float* __restrict__ gam,
                                                 const float* __restrict__ bet,
                                                 float* __restrict__ integ,
                                                 unsigned short* __restrict__ out) {
  const int row = blockIdx.x;
  const int node = blockIdx.y;
  const int tid = threadIdx.x;
  const long long rowoff = (long long)row * 1024 + tid * 4;
  const long long base = (long long)node * BD + rowoff;
  float4 v;
  if (ADJ) {
    v = make_float4(0.f, 0.f, 0.f, 0.f);
    const int r = node / 3, c = node % 3;
    if (r > 0) { float4 t = *(const float4*)(in + (node - 3) * BD + rowoff); v.x += t.x; v.y += t.y; v.z += t.z; v.w += t.w; }
    if (r < 2) { float4 t = *(const float4*)(in + (node + 3) * BD + rowoff); v.x += t.x; v.y += t.y; v.z += t.z; v.w += t.w; }
    if (c > 0) { float4 t = *(const float4*)(in + (node - 1) * BD + rowoff); v.x += t.x; v.y += t.y; v.z += t.z; v.w += t.w; }
    if (c < 2) { float4 t = *(const float4*)(in + (node + 1) * BD + rowoff); v.x += t.x; v.y += t.y; v.z += t.z; v.w += t.w; }
    *(float4*)(integ + base) = v;
  } else {
    v = *(const float4*)(in + base);
  }
  float s = v.x + v.y + v.z + v.w;
  float q = v.x * v.x + v.y * v.y + v.z * v.z + v.w * v.w;
  for (int off = 32; off > 0; off >>= 1) {
    s += __shfl_down(s, off);
    q += __shfl_down(q, off);
  }
  __shared__ float red[8];
  if ((tid & 63) == 0) { red[tid >> 6] = s; red[4 + (tid >> 6)] = q; }
  __syncthreads();
  s = red[0] + red[1] + red[2] + red[3];
  q = red[4] + red[5] + red[6] + red[7];
  const float mean = s * (1.0f / 1024.0f);
  const float var = q * (1.0f / 1024.0f) - mean * mean;
  const float inv = rsqrtf(var + 1e-5f);
  const float4 g = *(const float4*)(gam + node * 1024 + tid * 4);
  const float4 b = *(const float4*)(bet + node * 1024 + tid * 4);
  const float o0 = (v.x - mean) * inv * g.x + b.x;
  const float o1 = (v.y - mean) * inv * g.y + b.y;
  const float o2 = (v.z - mean) * inv * g.z + b.z;
  const float o3 = (v.w - mean) * inv * g.w + b.w;
  unsigned int lo = (unsigned int)f2bf(o0) | ((unsigned int)f2bf(o1) << 16);
  unsigned int hi = (unsigned int)f2bf(o2) | ((unsigned int)f2bf(o3) << 16);
  *(uint2*)(out + base) = make_uint2(lo, hi);
}

// ---------------------------------------------------------------------------
// Fused attention-combine + memory EMA + LN2.
// x = integ + bf16(attn) + cb; mem nodes: x = 0.7*mem + 0.3*x, mem <- x;
// S <- x (fp32); xn2 <- LN2(x) (bf16).  One (node,row) per 256-thread block.
__global__ __launch_bounds__(256) void combine_kernel(
    const float* __restrict__ integ,
    const unsigned short* __restrict__ attn,
    const float* __restrict__ cb,
    const float* __restrict__ gam, const float* __restrict__ bet,
    float* __restrict__ membuf,
    float* __restrict__ S,
    unsigned short* __restrict__ xn2) {
  const int row = blockIdx.x;
  const int node = blockIdx.y;
  const int tid = threadIdx.x;
  const long long rowoff = (long long)row * 1024 + tid * 4;
  const long long base = (long long)node * BD + rowoff;

  float4 v = *(const float4*)(integ + base);
  const uint2 a = *(const uint2*)(attn + base);
  const float4 c = *(const float4*)(cb + node * 1024 + tid * 4);
  v.x += bf2f((unsigned short)(a.x & 0xffffu)) + c.x;
  v.y += bf2f((unsigned short)(a.x >> 16)) + c.y;
  v.z += bf2f((unsigned short)(a.y & 0xffffu)) + c.z;
  v.w += bf2f((unsigned short)(a.y >> 16)) + c.w;

  const bool is_mem = (node != 4) && ((node & 1) == 0);
  if (is_mem) {
    const int mi = (node == 0) ? 0 : (node == 2) ? 1 : (node == 6) ? 2 : 3;
    float* mz = membuf + (long long)mi * BD + rowoff;
    const float4 m = *(const float4*)mz;
    v.x = 0.7f * m.x + 0.3f * v.x;
    v.y = 0.7f * m.y + 0.3f * v.y;
    v.z = 0.7f * m.z + 0.3f * v.z;
    v.w = 0.7f * m.w + 0.3f * v.w;
    *(float4*)mz = v;
  }
  *(float4*)(S + base) = v;

  float s = v.x + v.y + v.z + v.w;
  float q = v.x * v.x + v.y * v.y + v.z * v.z + v.w * v.w;
  for (int off = 32; off > 0; off >>= 1) {
    s += __shfl_down(s, off);
    q += __shfl_down(q, off);
  }
  __shared__ float red[8];
  if ((tid & 63) == 0) { red[tid >> 6] = s; red[4 + (tid >> 6)] = q; }
  __syncthreads();
  s = red[0] + red[1] + red[2] + red[3];
  q = red[4] + red[5] + red[6] + red[7];
  const float mean = s * (1.0f / 1024.0f);
  const float var = q * (1.0f / 1024.0f) - mean * mean;
  const float inv = rsqrtf(var + 1e-5f);
  const float4 g = *(const float4*)(gam + node * 1024 + tid * 4);
  const float4 b = *(const float4*)(bet + node * 1024 + tid * 4);
  const float o0 = (v.x - mean) * inv * g.x + b.x;
  const float o1 = (v.y - mean) * inv * g.y + b.y;
  const float o2 = (v.z - mean) * inv * g.z + b.z;
  const float o3 = (v.w - mean) * inv * g.w + b.w;
  unsigned int lo = (unsigned int)f2bf(o0) | ((unsigned int)f2bf(o1) << 16);
  unsigned int hi = (unsigned int)f2bf(o2) | ((unsigned int)f2bf(o3) << 16);
  *(uint2*)(xn2 + base) = make_uint2(lo, hi);
}

// ---------------------------------------------------------------------------
// 256x256 / BK=64 8-phase pipelined GEMM (HK-style schedule, plain HIP).
// 512 threads = 8 waves (2M x 4N), per-wave output 128x64 (acc[8][4]).
// LDS 128 KiB: [buf][A/B][khalf][256 rows x 32 bf16], chunk-XOR swizzled.
// Staging via global_load_lds 16B, 1 half-tile (2 loads) per phase; counted
// vmcnt(6) at phases 4/8 only (never 0 in steady state); setprio around MFMA.
// MODE 2: out bf16 = relu(acc + bias)     (FFN layer 1)
// MODE 4: out bf16 = acc (no bias)        (attn / wc / split-K partials)
template <int MODE>
__global__ __launch_bounds__(512, 2) void gemm256_kernel(
    const unsigned short* __restrict__ X, long long sX,
    const unsigned short* __restrict__ W, long long sW,
    const float* __restrict__ bias, int sBias,
    void* __restrict__ outp, long long sOut,
    int N, int K, int SK) {
  __shared__ __attribute__((aligned(16))) unsigned short lds[2][2][2][8192];
  const int z = blockIdx.z;
  const int node = z / SK;
  const int kz = z - node * SK;
  const int Kper = K / SK;
  const int kbeg = kz * Kper;
  const long long bm = (long long)blockIdx.y * 256;
  const long long bn = (long long)blockIdx.x * 256;
  const unsigned short* Xz = X + (long long)node * sX;
  const unsigned short* Wz = W + (long long)node * sW;
  const int tid = threadIdx.x;
  const int lane = tid & 63;
  const int wid = tid >> 6;
  const int wrow = (wid >> 2) * 128;   // wave M base within tile
  const int wcol = (wid & 3) * 64;     // wave N base within tile
  const int lm = lane & 15;
  const int quad = lane >> 4;
  const int lrow = lane >> 2;
  const int gch = ((lane & 3) ^ ((lane >> 3) & 3)) * 8;  // swizzled global k-chunk
  const int fch = (quad ^ ((lm >> 1) & 3)) * 8;          // fragment-read chunk

  f32x4 acc[8][4] = {};
  bf16x8 af[4][2], bfv[4][2];

  // per-wave 16-row staging groups
  const int GA = (wid & 3) + ((wid >> 2) << 3);       // A0: {0-3,8-11}; A1 = +4
  const int GB = ((wid >> 1) << 2) + (wid & 1);       // B0: {0,1,4,5,...}; B1 = +2
  const unsigned short* pA[2] = {
      Xz + (bm + (long long)GA * 16 + lrow) * K + gch,
      Xz + (bm + (long long)(GA + 4) * 16 + lrow) * K + gch };
  const unsigned short* pB[2] = {
      Wz + (bn + (long long)GB * 16 + lrow) * K + gch,
      Wz + (bn + (long long)(GB + 2) * 16 + lrow) * K + gch };
  const int dA[2] = { GA * 512, (GA + 4) * 512 };
  const int dB[2] = { GB * 512, (GB + 2) * 512 };

  // one half-tile = 128 rows x 64 cols = 2 x global_load_lds (kh0, kh1)
  auto stageA = [&](int buf, int t, int hi) {
    const unsigned short* g = pA[hi] + kbeg + (long long)t * 64;
    gl_lds16(g,      &lds[buf][0][0][dA[hi]]);
    gl_lds16(g + 32, &lds[buf][0][1][dA[hi]]);
  };
  auto stageB = [&](int buf, int t, int hi) {
    const unsigned short* g = pB[hi] + kbeg + (long long)t * 64;
    gl_lds16(g,      &lds[buf][1][0][dB[hi]]);
    gl_lds16(g + 32, &lds[buf][1][1][dB[hi]]);
  };

#define LDA_HALF(BUF, IH)                                                      \
  _Pragma("unroll") for (int i_ = 0; i_ < 4; ++i_)                             \
      _Pragma("unroll") for (int k_ = 0; k_ < 2; ++k_)                         \
          af[i_][k_] = *(const bf16x8*)&lds[BUF][0][k_]                        \
              [(wrow + (IH) * 64 + i_ * 16 + lm) * 32 + fch];

#define LDB_HALF(BUF, JH)                                                      \
  _Pragma("unroll") for (int j_ = 0; j_ < 2; ++j_)                             \
      _Pragma("unroll") for (int k_ = 0; k_ < 2; ++k_)                         \
          bfv[(JH) * 2 + j_][k_] = *(const bf16x8*)&lds[BUF][1][k_]            \
              [(wcol + (JH) * 32 + j_ * 16 + lm) * 32 + fch];

#define MFMA_Q(IH, JH)                                                         \
  _Pragma("unroll") for (int i_ = 0; i_ < 4; ++i_)                             \
      _Pragma("unroll") for (int j_ = 0; j_ < 2; ++j_)                         \
          _Pragma("unroll") for (int k_ = 0; k_ < 2; ++k_)                     \
              acc[(IH) * 4 + i_][(JH) * 2 + j_] =                              \
                  __builtin_amdgcn_mfma_f32_16x16x32_bf16(                     \
                      af[i_][k_], bfv[(JH) * 2 + j_][k_],                      \
                      acc[(IH) * 4 + i_][(JH) * 2 + j_], 0, 0, 0);

#define PH_MID()                                          \
  __builtin_amdgcn_s_barrier();                           \
  asm volatile("s_waitcnt lgkmcnt(0)" ::: "memory");      \
  __builtin_amdgcn_s_setprio(1);

#define PH_END()                                          \
  __builtin_amdgcn_s_setprio(0);                          \
  __builtin_amdgcn_s_barrier();

  const int NIT = Kper >> 7;   // tile-pairs (2 x BK=64 per iteration)

  // Prologue: tile 0 fully (A0,B0,B1,A1) + tile 1 (A0,B0,B1) = 14 loads.
  stageA(0, 0, 0); stageB(0, 0, 0); stageB(0, 0, 1); stageA(0, 0, 1);
  stageA(1, 1, 0); stageB(1, 1, 0); stageB(1, 1, 1);
  asm volatile("s_waitcnt vmcnt(6)" ::: "memory");   // tile 0 landed
  __builtin_amdgcn_s_barrier();

#pragma unroll 1
  for (int I = 0; I < NIT; ++I) {
    const bool notlast = (I + 1 < NIT);
    const int t0 = 2 * I;
    // phase 1: Q(0,0) of tile t0 (buf0); stage A1 of tile t0+1 -> buf1
    LDA_HALF(0, 0) LDB_HALF(0, 0)
    stageA(1, t0 + 1, 1);
    PH_MID() MFMA_Q(0, 0) PH_END()
    // phase 2: Q(0,1); stage A0 of t0+2 -> buf0 (region read in ph1)
    LDB_HALF(0, 1)
    if (notlast) stageA(0, t0 + 2, 0);
    PH_MID() MFMA_Q(0, 1) PH_END()
    // phase 3: Q(1,0); stage B0 of t0+2
    LDA_HALF(0, 1)
    if (notlast) stageB(0, t0 + 2, 0);
    PH_MID() MFMA_Q(1, 0) PH_END()
    // phase 4: Q(1,1); stage B1 of t0+2; counted wait for tile t0+1
    if (notlast) stageB(0, t0 + 2, 1);
    PH_MID() MFMA_Q(1, 1)
    __builtin_amdgcn_s_setprio(0);
    if (notlast) asm volatile("s_waitcnt vmcnt(6)" ::: "memory");
    else         asm volatile("s_waitcnt vmcnt(0)" ::: "memory");
    __builtin_amdgcn_s_barrier();
    // phase 5: Q(0,0) of tile t0+1 (buf1); stage A1 of t0+2
    LDA_HALF(1, 0) LDB_HALF(1, 0)
    if (notlast) stageA(0, t0 + 2, 1);
    PH_MID() MFMA_Q(0, 0) PH_END()
    // phase 6: Q(0,1); stage A0 of t0+3 -> buf1
    LDB_HALF(1, 1)
    if (notlast) stageA(1, t0 + 3, 0);
    PH_MID() MFMA_Q(0, 1) PH_END()
    // phase 7: Q(1,0); stage B0 of t0+3
    LDA_HALF(1, 1)
    if (notlast) stageB(1, t0 + 3, 0);
    PH_MID() MFMA_Q(1, 0) PH_END()
    // phase 8: Q(1,1); stage B1 of t0+3; counted wait for tile t0+2
    if (notlast) stageB(1, t0 + 3, 1);
    PH_MID() MFMA_Q(1, 1)
    __builtin_amdgcn_s_setprio(0);
    if (notlast) asm volatile("s_waitcnt vmcnt(6)" ::: "memory");
    __builtin_amdgcn_s_barrier();
  }

  // Epilogue.  C/D layout: col = lane&15, row = quad*4 + reg
  if (MODE == 2) {
    const float* bz = bias + (long long)node * sBias;
    unsigned short* out = (unsigned short*)outp + (long long)node * sOut;
#pragma unroll
    for (int i = 0; i < 8; ++i) {
      const long long rb = bm + wrow + i * 16 + quad * 4;
#pragma unroll
      for (int j = 0; j < 4; ++j) {
        const int col = (int)bn + wcol + j * 16 + lm;
        const float bv = bz[col];
#pragma unroll
        for (int r = 0; r < 4; ++r)
          out[(rb + r) * (long long)N + col] = f2bf(fmaxf(acc[i][j][r] + bv, 0.0f));
      }
    }
  } else {  // MODE 4
    unsigned short* out = (unsigned short*)outp + (long long)z * sOut;
#pragma unroll
    for (int i = 0; i < 8; ++i) {
      const long long rb = bm + wrow + i * 16 + quad * 4;
#pragma unroll
      for (int j = 0; j < 4; ++j) {
        const int col = (int)bn + wcol + j * 16 + lm;
#pragma unroll
        for (int r = 0; r < 4; ++r)
          out[(rb + r) * (long long)N + col] = f2bf(acc[i][j][r]);
      }
    }
  }
#undef LDA_HALF
#undef LDB_HALF
#undef MFMA_Q
#undef PH_MID
#undef PH_END
}

// ---------------------------------------------------------------------------
// Split-K reduce: S[node] += sum_kz partial[kz] + bias.  bf16 partials.
__global__ __launch_bounds__(256) void reduce_kernel(const unsigned short* __restrict__ part_s,
                                                     const unsigned short* __restrict__ part_e,
                                                     const float* __restrict__ b2s,
                                                     const float* __restrict__ b2e,
                                                     float* __restrict__ S) {
  const int node = blockIdx.y;
  const long long i8 = ((long long)blockIdx.x * 256 + threadIdx.x) * 8;
  const int col = (int)(i8 & 1023);
  const unsigned short* base;
  const float* bias;
  int SKn;
  if (node & 1) {
    const int e = (node - 1) >> 1;
    base = part_e + (long long)(e * 4) * BD + i8;
    bias = b2e + e * 1024;
    SKn = 4;
  } else {
    const int si = node >> 1;
    base = part_s + (long long)(si * 2) * BD + i8;
    bias = b2s + si * 1024;
    SKn = 2;
  }
  float sum[8] = {};
  for (int kz = 0; kz < SKn; ++kz) {
    uint4 p = *(const uint4*)(base + (long long)kz * BD);
    const unsigned short* ph = (const unsigned short*)&p;
#pragma unroll
    for (int j = 0; j < 8; ++j) sum[j] += bf2f(ph[j]);
  }
  float* sp = S + (long long)node * BD + i8;
  float4 s0 = *(float4*)sp;
  float4 s1 = *(float4*)(sp + 4);
  s0.x += sum[0] + bias[col + 0];
  s0.y += sum[1] + bias[col + 1];
  s0.z += sum[2] + bias[col + 2];
  s0.w += sum[3] + bias[col + 3];
  s1.x += sum[4] + bias[col + 4];
  s1.y += sum[5] + bias[col + 5];
  s1.z += sum[6] + bias[col + 6];
  s1.w += sum[7] + bias[col + 7];
  *(float4*)sp = s0;
  *(float4*)(sp + 4) = s1;
}

// ---------------------------------------------------------------------------
extern "C" void kernel_launch(void* const* d_in, const int* in_sizes, int n_in,
                              void* d_out, int out_size, void* d_ws, size_t ws_size,
                              hipStream_t stream) {
  const float* seed  = (const float*)d_in[0];
  const float* ln1_s = (const float*)d_in[1];
  const float* ln1_b = (const float*)d_in[2];
  const float* v_w   = (const float*)d_in[3];
  const float* v_b   = (const float*)d_in[4];
  const float* o_w   = (const float*)d_in[5];
  const float* o_b   = (const float*)d_in[6];
  const float* ln2_s = (const float*)d_in[7];
  const float* ln2_b = (const float*)d_in[8];
  const float* w1_s  = (const float*)d_in[9];
  const float* b1_s  = (const float*)d_in[10];
  const float* w2_s  = (const float*)d_in[11];
  const float* b2_s  = (const float*)d_in[12];
  const float* w1_e  = (const float*)d_in[13];
  const float* b1_e  = (const float*)d_in[14];
  const float* w2_e  = (const float*)d_in[15];
  const float* b2_e  = (const float*)d_in[16];

  char* ws = (char*)d_ws;
  size_t off = 0;
  auto alloc = [&](long long elems, int esize) {
    void* p = ws + off;
    off += (size_t)((elems * esize + 255LL) & ~255LL);
    return p;
  };
  unsigned short* wo    = (unsigned short*)alloc(9 * BD, 2);
  unsigned short* vwT   = (unsigned short*)alloc(9 * BD, 2);
  unsigned short* wc    = (unsigned short*)alloc(9 * BD, 2);
  unsigned short* w1s   = (unsigned short*)alloc(10 * BD, 2);
  unsigned short* w2s   = (unsigned short*)alloc(10 * BD, 2);
  unsigned short* w1e   = (unsigned short*)alloc(32 * BD, 2);
  unsigned short* w2e   = (unsigned short*)alloc(32 * BD, 2);
  float*          membuf= (float*)alloc(4 * BD, 4);
  float*          cb    = (float*)alloc(9 * 1024, 4);
  // union region: {integ fp32 + xn bf16} (54 MB)  <->  {part_s + part_e} (52 MB)
  char* region = (char*)alloc(9 * BD * 4 + 9 * BD * 2, 1);
  float*          integ  = (float*)region;
  unsigned short* xn     = (unsigned short*)(region + 9 * BD * 4);
  unsigned short* part_s = (unsigned short*)region;                 // 10 planes bf16
  unsigned short* part_e = (unsigned short*)(region + 10 * BD * 2); // 16 planes bf16
  unsigned short* hs    = (unsigned short*)alloc(10 * BD, 2);
  unsigned short* he    = (unsigned short*)alloc(32 * BD, 2);
  // attn partial plane (9 x BD bf16 = 18 MB) aliases he (64 MB):
  // written by attn gemm (before combine), dead before ffn1e writes he.
  unsigned short* att_p = he;

  float* S = (float*)d_out;  // S lives in d_out; also aliases x within a step

  // One-time (per launch): weight conversion, combined attention weight, init
  cvt_kernel<<<(unsigned)(9  * BD / 1024), 256, 0, stream>>>(o_w,  wo,  9  * BD / 4);
  tcvt_kernel<<<dim3(32, 32, 9), 256, 0, stream>>>(v_w, vwT);
  cvt_kernel<<<(unsigned)(10 * BD / 1024), 256, 0, stream>>>(w1_s, w1s, 10 * BD / 4);
  cvt_kernel<<<(unsigned)(10 * BD / 1024), 256, 0, stream>>>(w2_s, w2s, 10 * BD / 4);
  cvt_kernel<<<(unsigned)(32 * BD / 1024), 256, 0, stream>>>(w1_e, w1e, 32 * BD / 4);
  cvt_kernel<<<(unsigned)(32 * BD / 1024), 256, 0, stream>>>(w2_e, w2e, 32 * BD / 4);
  cb_kernel<<<dim3(256, 9), 256, 0, stream>>>(o_w, v_b, o_b, cb);
  // wc[n] = o_w[n] . v_w[n]  (combined attention weight, bf16)
  gemm256_kernel<4><<<dim3(4, 4, 9), 512, 0, stream>>>(
      wo, BD, vwT, BD, nullptr, 0, (void*)wc, BD, 1024, 1024, 1);
  init_kernel<<<(unsigned)(13 * BD / 1024), 256, 0, stream>>>(seed, S, membuf);

  for (int step = 0; step < 3; ++step) {
    // integ = A@S ; xn = LN1(integ)
    ln_kernel<true><<<dim3(1024, 9), 256, 0, stream>>>(S, ln1_s, ln1_b, integ, xn);
    // att_p = xn @ wc^T  (bf16, no bias)
    gemm256_kernel<4><<<dim3(4, 4, 9), 512, 0, stream>>>(
        xn, BD, wc, BD, nullptr, 0, (void*)att_p, BD, 1024, 1024, 1);
    // x = integ + att_p + cb; mem EMA; S <- x; xn2 <- LN2(x)
    combine_kernel<<<dim3(1024, 9), 256, 0, stream>>>(
        integ, att_p, cb, ln2_s, ln2_b, membuf, S, xn);
    // hs = relu(xn2[sids] @ w1_s^T + b1_s)   nodes {0,2,4,6,8}
    gemm256_kernel<2><<<dim3(8, 4, 5), 512, 0, stream>>>(
        xn, 2 * BD, w1s, 2 * BD, b1_s, 2048, (void*)hs, 2 * BD, 2048, 1024, 1);
    // he = relu(xn2[eids] @ w1_e^T + b1_e)   nodes {1,3,5,7}
    gemm256_kernel<2><<<dim3(32, 4, 4), 512, 0, stream>>>(
        xn + BD, 2 * BD, w1e, 8 * BD, b1_e, 8192, (void*)he, 8 * BD, 8192, 1024, 1);
    // split-K partials: part_s[si*2+kz] = (hs @ w2_s^T)  (160 blocks)
    gemm256_kernel<4><<<dim3(4, 4, 10), 512, 0, stream>>>(
        hs, 2 * BD, w2s, 2 * BD, nullptr, 0, (void*)part_s, BD, 1024, 2048, 2);
    // split-K partials: part_e[e*4+kz] = (he @ w2_e^T)   (256 blocks)
    gemm256_kernel<4><<<dim3(4, 4, 16), 512, 0, stream>>>(
        he, 8 * BD, w2e, 8 * BD, nullptr, 0, (void*)part_e, BD, 1024, 8192, 4);
    // S += sum(partials) + b2
    reduce_kernel<<<dim3(512, 9), 256, 0, stream>>>(part_s, part_e, b2_s, b2_e, S);
  }
}